// Round 8
// baseline (6550.608 us; speedup 1.0000x reference)
//
#include <hip/hip_runtime.h>
#include <stdint.h>

// Problem constants
constexpr int T_STEPS = 512;
constexpr int BSZ     = 256;
constexpr int OBSD    = 64;
constexpr int HID     = 512;
constexpr int NROWS   = T_STEPS * BSZ;   // 131072

// LSTM partitioning: 8 groups x 32 WGs; group owns 32 batch rows; WG owns 16 h-cols
// group = wg & 7 -> under round-robin dispatch all members land on one XCD.
constexpr int GROUPS = 8;
constexpr int WPG    = 32;
constexpr int BW     = 32;
constexpr int TEST_BUDGET = 50000;

typedef __attribute__((ext_vector_type(8))) short bf16x8;
typedef __attribute__((ext_vector_type(4))) float f32x4;

__device__ __forceinline__ float bf2f(uint16_t u) {
  union { uint32_t i; float f; } v; v.i = ((uint32_t)u) << 16; return v.f;
}
__device__ __forceinline__ uint16_t f2bf(float f) {
  union { float f; uint32_t i; } v; v.f = f;
  return (uint16_t)((v.i + 0x7FFFu + ((v.i >> 16) & 1u)) >> 16);
}
__device__ __forceinline__ uint64_t pack4(float a, float b, float c, float d) {
  uint32_t lo = (uint32_t)f2bf(a) | ((uint32_t)f2bf(b) << 16);
  uint32_t hi = (uint32_t)f2bf(c) | ((uint32_t)f2bf(d) << 16);
  return (uint64_t)lo | ((uint64_t)hi << 32);
}
__device__ __forceinline__ float sigm(float x) { return 1.f / (1.f + __expf(-x)); }
__device__ __forceinline__ float tanh_fast(float x) {
  float e = __expf(2.f * x);
  return 1.f - 2.f / (e + 1.f);
}

__device__ __forceinline__ void gll16(const void* g, void* l) {
  __builtin_amdgcn_global_load_lds(
      (const __attribute__((address_space(1))) uint32_t*)g,
      (__attribute__((address_space(3))) uint32_t*)l, 16, 0, 0);
}

// ---------------------------------------------------------------------------
// Persistent LSTM scan. 256 blocks x 256 threads, 1 block/CU.
// SLOW path == round-5 protocol (proven): agent-scope (LIC) h/flag traffic.
// FAST path (XCD-L2 transport, validated each launch by a bounded self-test):
//   plain stores (write-through to XCD L2) + sc0 loads (L1-bypass, L2-served).
// Polling discipline (round-7 lesson: unthrottled polls saturate the L2 bank
// holding the flag line): ONLY wave 0 polls, with s_sleep(1) backoff; other
// waves wait at __syncthreads.
// MFMA partition: wave = 2 gates x 16 rows -> 18 ds_read_b128/wave (halved);
// weights = 36 bf16x8 = 144 VGPR/wave (1 wave/SIMD -> 512 VGPR budget).
// ---------------------------------------------------------------------------
__global__ __launch_bounds__(256, 1) void lstm_kernel(
    const float* __restrict__ xin, const float* __restrict__ done,
    const float* __restrict__ h0, const float* __restrict__ c0,
    const float* __restrict__ W_ih, const float* __restrict__ W_hh,
    const float* __restrict__ b_ih, const float* __restrict__ b_hh,
    uint16_t* __restrict__ hs, uint32_t* __restrict__ flg,
    uint32_t* __restrict__ slotxcd, uint32_t* __restrict__ vslot,
    uint32_t* __restrict__ tloc, float* __restrict__ out)
{
  __shared__ char  Ab[32 * 1152];
  __shared__ float gl[4 * 544];     // [gate][32 rows][17 pad]
  __shared__ float bl[64];
  __shared__ int   s_fast;

  const int wg   = blockIdx.x;
  const int g    = wg & 7;          // group == presumed XCD
  const int win  = wg >> 3;         // slot within group: h-col slice
  const int bg   = g * BW;
  const int tid  = threadIdx.x;
  const int lane = tid & 63;
  const int q    = tid >> 6;        // wave id

  // one-time: drop any stale L1/L2 lines from a previous graph replay
  __builtin_amdgcn_fence(__ATOMIC_ACQUIRE, "agent");

  // ---- publish my XCD id (proven agent path) ----
  uint32_t xcd;
  asm volatile("s_getreg_b32 %0, hwreg(HW_REG_XCC_ID)" : "=s"(xcd));
  if (tid == 0)
    __hip_atomic_store(slotxcd + g * 32 + win, xcd | 0x100u,
                       __ATOMIC_RELAXED, __HIP_MEMORY_SCOPE_AGENT);

  // ---- one-time: weight fragments into VGPRs. wave q: gates gp, gp+1 ----
  const int gp   = (q >> 1) * 2;    // gate pair base
  const int rblk = (q & 1) * 16;    // row block for MFMA
  bf16x8 bqA[18], bqB[18];
  {
    const int rowA = gp * 512 + win * 16 + (lane & 15);
    const int rowB = (gp + 1) * 512 + win * 16 + (lane & 15);
    const int kg8  = (lane >> 4) * 8;
    #pragma unroll
    for (int ks = 0; ks < 18; ++ks) {
      const float* srcA = (ks < 16)
          ? (W_hh + (size_t)rowA * 512 + ks * 32 + kg8)
          : (W_ih + (size_t)rowA * 64 + (ks - 16) * 32 + kg8);
      const float* srcB = (ks < 16)
          ? (W_hh + (size_t)rowB * 512 + ks * 32 + kg8)
          : (W_ih + (size_t)rowB * 64 + (ks - 16) * 32 + kg8);
      float4 a0 = *(const float4*)srcA;
      float4 a1 = *(const float4*)(srcA + 4);
      float4 b0 = *(const float4*)srcB;
      float4 b1 = *(const float4*)(srcB + 4);
      bf16x8 va, vb;
      va[0] = (short)f2bf(a0.x); va[1] = (short)f2bf(a0.y);
      va[2] = (short)f2bf(a0.z); va[3] = (short)f2bf(a0.w);
      va[4] = (short)f2bf(a1.x); va[5] = (short)f2bf(a1.y);
      va[6] = (short)f2bf(a1.z); va[7] = (short)f2bf(a1.w);
      vb[0] = (short)f2bf(b0.x); vb[1] = (short)f2bf(b0.y);
      vb[2] = (short)f2bf(b0.z); vb[3] = (short)f2bf(b0.w);
      vb[4] = (short)f2bf(b1.x); vb[5] = (short)f2bf(b1.y);
      vb[6] = (short)f2bf(b1.z); vb[7] = (short)f2bf(b1.w);
      bqA[ks] = va; bqB[ks] = vb;
    }
  }
  if (tid < 64) {
    int q2 = tid >> 4, c = tid & 15;
    int grow = q2 * 512 + win * 16 + c;
    bl[tid] = b_ih[grow] + b_hh[grow];
  }

  // ---- wave 0: cleanliness collect + hardware self-test + verdict ----
  if (q == 0) {
    uint32_t v = 0;
    if (lane < WPG) {
      for (;;) {
        v = __hip_atomic_load(slotxcd + g * 32 + lane,
                              __ATOMIC_RELAXED, __HIP_MEMORY_SCOPE_AGENT);
        if (v != 0) break;
        __builtin_amdgcn_s_sleep(1);
      }
    }
    bool alleq = __all((int)((lane < WPG) ? (v == (xcd | 0x100u)) : 1));

    int pass = 0;
    if (alleq) {
      if (win == 0 && lane == 0) {
        for (int d = 0; d < 100; ++d) __builtin_amdgcn_s_sleep(4);
        __hip_atomic_store(tloc + g, 1u, __ATOMIC_RELAXED, __HIP_MEMORY_SCOPE_WORKGROUP);
        asm volatile("s_waitcnt vmcnt(0)" ::: "memory");
        for (int d = 0; d < 100; ++d) __builtin_amdgcn_s_sleep(4);
        __hip_atomic_store(tloc + g, 2u, __ATOMIC_RELAXED, __HIP_MEMORY_SCOPE_WORKGROUP);
        asm volatile("s_waitcnt vmcnt(0)" ::: "memory");
      }
      bool p1 = false, p2 = false;
      for (int it = 0; it < TEST_BUDGET; ++it) {
        uint32_t tv;
        asm volatile("global_load_dword %0, %1, off sc0\n\ts_waitcnt vmcnt(0)"
                     : "=v"(tv) : "v"(tloc + g) : "memory");
        if (tv >= 1u) { p1 = true; break; }
      }
      if (p1) {
        for (int it = 0; it < TEST_BUDGET; ++it) {
          uint32_t tv;
          asm volatile("global_load_dword %0, %1, off sc0\n\ts_waitcnt vmcnt(0)"
                       : "=v"(tv) : "v"(tloc + g) : "memory");
          if (tv >= 2u) { p2 = true; break; }
        }
      }
      pass = (p1 && p2) ? 1 : 0;
    }
    if (lane == 0)
      __hip_atomic_store(vslot + g * 32 + win, pass ? 2u : 1u,
                         __ATOMIC_RELAXED, __HIP_MEMORY_SCOPE_AGENT);
    uint32_t pv = 0;
    if (lane < WPG) {
      for (;;) {
        pv = __hip_atomic_load(vslot + g * 32 + lane,
                               __ATOMIC_RELAXED, __HIP_MEMORY_SCOPE_AGENT);
        if (pv != 0) break;
        __builtin_amdgcn_s_sleep(1);
      }
    }
    bool allpass = __all((int)((lane < WPG) ? (pv == 2u) : 1));
    if (lane == 0) s_fast = allpass ? 1 : 0;
  }

  const int b_loc = tid >> 3;        // 0..31 (batch row within group)
  const int n0    = (tid & 7) * 2;   // h-col pair within WG's 16 cols
  float creg0 = c0[(size_t)(bg + b_loc) * HID + win * 16 + n0];
  float creg1 = c0[(size_t)(bg + b_loc) * HID + win * 16 + n0 + 1];

  const int sr  = tid >> 3;          // x staging row
  const int sc8 = (tid & 7) * 8;     // x col base
  const int rw  = q * 8;             // wave's h staging rows

  __syncthreads();
  const bool fast = (s_fast != 0);

  for (int t = 0; t < T_STEPS; ++t) {
    // ---- hoisted loads (overlap the poll): x_t, done values ----
    const float* xp = xin + ((size_t)t * BSZ + bg + sr) * OBSD + sc8;
    float4 xa = *(const float4*)xp;
    float4 xb = *(const float4*)(xp + 4);
    float dvs[8];
    #pragma unroll
    for (int r8 = 0; r8 < 8; ++r8)
      dvs[r8] = done[(size_t)t * BSZ + bg + rw + r8];
    float dv_b = done[(size_t)t * BSZ + bg + b_loc];

    // stage x_t into Ab (end-of-prev-step barrier -> no race with MFMA)
    {
      uint4 u4;
      u4.x = (uint32_t)f2bf(xa.x) | ((uint32_t)f2bf(xa.y) << 16);
      u4.y = (uint32_t)f2bf(xa.z) | ((uint32_t)f2bf(xa.w) << 16);
      u4.z = (uint32_t)f2bf(xb.x) | ((uint32_t)f2bf(xb.y) << 16);
      u4.w = (uint32_t)f2bf(xb.z) | ((uint32_t)f2bf(xb.w) << 16);
      *(uint4*)(Ab + ((sr * 1152 + 1024 + sc8 * 2) ^ ((sr & 7) << 4))) = u4;
    }

    // ---- wave 0 polls group flags (throttled); barrier releases the rest ----
    if (t > 0) {
      if (q == 0) {
        if (fast) {
          for (;;) {
            uint32_t f = 0xFFFFFFFFu;
            if (lane < WPG) {
              asm volatile("global_load_dword %0, %1, off sc0\n\ts_waitcnt vmcnt(0)"
                           : "=v"(f) : "v"(flg + g * 32 + lane) : "memory");
            }
            if (__all((int)(f >= (uint32_t)t))) break;
            __builtin_amdgcn_s_sleep(1);
          }
        } else {
          for (;;) {
            uint32_t f = (lane < WPG)
                ? __hip_atomic_load(flg + g * 32 + lane, __ATOMIC_RELAXED, __HIP_MEMORY_SCOPE_AGENT)
                : 0xFFFFFFFFu;
            if (__all((int)(f >= (uint32_t)t))) break;
            __builtin_amdgcn_s_sleep(1);
          }
        }
        __builtin_amdgcn_fence(__ATOMIC_ACQUIRE, "workgroup");
      }
      __syncthreads();
    }

    // ---- stage h_{t-1}: wave loads its 8 rows, coalesced 512B per instr ----
    if (t == 0) {
      #pragma unroll
      for (int r8 = 0; r8 < 8; ++r8) {
        int r = rw + r8;
        uint64_t v0 = 0, v1 = 0;
        if (dvs[r8] <= 0.5f) {
          const float* hp = h0 + (size_t)(bg + r) * HID;
          float4 ha = *(const float4*)(hp + lane * 4);
          float4 hb = *(const float4*)(hp + 256 + lane * 4);
          v0 = pack4(ha.x, ha.y, ha.z, ha.w);
          v1 = pack4(hb.x, hb.y, hb.z, hb.w);
        }
        *(uint64_t*)(Ab + ((r * 1152 + lane * 8) ^ ((r & 7) << 4))) = v0;
        *(uint64_t*)(Ab + ((r * 1152 + 512 + lane * 8) ^ ((r & 7) << 4))) = v1;
      }
    } else if (fast) {
      // FAST: sc0 loads served by the XCD-shared L2
      uint64_t hv0[8], hv1[8];
      const uint64_t* hb = (const uint64_t*)hs + ((size_t)(t - 1) * BSZ + bg) * 128;
      #pragma unroll
      for (int r8 = 0; r8 < 8; ++r8) {
        const uint64_t* hrow = hb + (size_t)(rw + r8) * 128;
        asm volatile("global_load_dwordx2 %0, %1, off sc0"
                     : "=v"(hv0[r8]) : "v"(hrow + lane));
        asm volatile("global_load_dwordx2 %0, %1, off sc0"
                     : "=v"(hv1[r8]) : "v"(hrow + 64 + lane));
      }
      asm volatile("s_waitcnt vmcnt(0)" ::: "memory");
      __builtin_amdgcn_sched_barrier(0);
      #pragma unroll
      for (int r8 = 0; r8 < 8; ++r8) {
        int r = rw + r8;
        uint64_t v0 = hv0[r8], v1 = hv1[r8];
        if (dvs[r8] > 0.5f) { v0 = 0; v1 = 0; }
        *(uint64_t*)(Ab + ((r * 1152 + lane * 8) ^ ((r & 7) << 4))) = v0;
        *(uint64_t*)(Ab + ((r * 1152 + 512 + lane * 8) ^ ((r & 7) << 4))) = v1;
      }
    } else {
      // SLOW: agent-scope (LIC) loads -- round-5 path
      #pragma unroll
      for (int r8 = 0; r8 < 8; ++r8) {
        int r = rw + r8;
        const uint64_t* hrow =
            (const uint64_t*)hs + ((size_t)(t - 1) * BSZ + bg + r) * 128;
        uint64_t v0 = __hip_atomic_load(hrow + lane, __ATOMIC_RELAXED, __HIP_MEMORY_SCOPE_AGENT);
        uint64_t v1 = __hip_atomic_load(hrow + 64 + lane, __ATOMIC_RELAXED, __HIP_MEMORY_SCOPE_AGENT);
        if (dvs[r8] > 0.5f) { v0 = 0; v1 = 0; }
        *(uint64_t*)(Ab + ((r * 1152 + lane * 8) ^ ((r & 7) << 4))) = v0;
        *(uint64_t*)(Ab + ((r * 1152 + 512 + lane * 8) ^ ((r & 7) << 4))) = v1;
      }
    }
    __syncthreads();

    // ---- MFMA: wave computes [16 rows x 16 cols] for gates gp and gp+1 ----
    f32x4 ac0 = {0.f, 0.f, 0.f, 0.f};
    f32x4 ac1 = {0.f, 0.f, 0.f, 0.f};
    {
      const int ar = rblk + (lane & 15);
      const int kg = lane >> 4;
      #pragma unroll
      for (int ks = 0; ks < 18; ++ks) {
        int kb = (ks * 32 + kg * 8) * 2;
        bf16x8 a = *(const bf16x8*)(Ab + ((ar * 1152 + kb) ^ ((ar & 7) << 4)));
        ac0 = __builtin_amdgcn_mfma_f32_16x16x32_bf16(a, bqA[ks], ac0, 0, 0, 0);
        ac1 = __builtin_amdgcn_mfma_f32_16x16x32_bf16(a, bqB[ks], ac1, 0, 0, 0);
      }
    }
    // ---- gates -> LDS exchange (rows padded to 17 words) ----
    {
      int c  = lane & 15;
      int rb = rblk + (lane >> 4) * 4;
      #pragma unroll
      for (int r = 0; r < 4; ++r) {
        gl[gp * 544 + (rb + r) * 17 + c]       = ac0[r];
        gl[(gp + 1) * 544 + (rb + r) * 17 + c] = ac1[r];
      }
    }
    __syncthreads();
    // ---- cell update (c lives in registers across all 512 steps) ----
    {
      float m = dv_b > 0.5f ? 0.f : 1.f;
      float h0v, h1v;
      {
        float I = gl[b_loc * 17 + n0]         + bl[n0];
        float F = gl[544 + b_loc * 17 + n0]   + bl[16 + n0];
        float G = gl[1088 + b_loc * 17 + n0]  + bl[32 + n0];
        float O = gl[1632 + b_loc * 17 + n0]  + bl[48 + n0];
        float cc = creg0 * m;
        cc = sigm(F) * cc + sigm(I) * tanh_fast(G);
        creg0 = cc;
        h0v = sigm(O) * tanh_fast(cc);
      }
      {
        int n1 = n0 + 1;
        float I = gl[b_loc * 17 + n1]         + bl[n1];
        float F = gl[544 + b_loc * 17 + n1]   + bl[16 + n1];
        float G = gl[1088 + b_loc * 17 + n1]  + bl[32 + n1];
        float O = gl[1632 + b_loc * 17 + n1]  + bl[48 + n1];
        float cc = creg1 * m;
        cc = sigm(F) * cc + sigm(I) * tanh_fast(G);
        creg1 = cc;
        h1v = sigm(O) * tanh_fast(cc);
      }
      uint32_t pk = (uint32_t)f2bf(h0v) | ((uint32_t)f2bf(h1v) << 16);
      uint32_t* hp = (uint32_t*)(hs + ((size_t)t * BSZ + bg + b_loc) * HID + win * 16 + n0);
      if (fast)
        __hip_atomic_store(hp, pk, __ATOMIC_RELAXED, __HIP_MEMORY_SCOPE_WORKGROUP);
      else
        __hip_atomic_store(hp, pk, __ATOMIC_RELAXED, __HIP_MEMORY_SCOPE_AGENT);
      if (t == T_STEPS - 1) {
        size_t ob = (size_t)(bg + b_loc) * HID + win * 16 + n0;
        out[NROWS + ob]         = h0v;
        out[NROWS + ob + 1]     = h1v;
        out[2 * NROWS + ob]     = creg0;
        out[2 * NROWS + ob + 1] = creg1;
      }
    }
    __syncthreads();   // per-wave vmcnt(0) drain -> h stores ACKed at L2/LIC
    if (tid == 0) {
      if (fast)
        __hip_atomic_store(flg + g * 32 + win, (uint32_t)(t + 1),
                           __ATOMIC_RELAXED, __HIP_MEMORY_SCOPE_WORKGROUP);
      else
        __hip_atomic_store(flg + g * 32 + win, (uint32_t)(t + 1),
                           __ATOMIC_RELAXED, __HIP_MEMORY_SCOPE_AGENT);
    }
  }
}

// ---------------------------------------------------------------------------
// Per-row LayerNorm stats from bf16 hidden: rstd[m], murs[m] = mu*rstd.
// ---------------------------------------------------------------------------
__global__ void ln_stats_kernel(const uint16_t* __restrict__ hsrc,
                                float* __restrict__ rstd_a, float* __restrict__ murs_a)
{
  const int lane = threadIdx.x & 63;
  const size_t row = (size_t)blockIdx.x * 4 + (threadIdx.x >> 6);
  bf16x8 v = *(const bf16x8*)(hsrc + row * 512 + lane * 8);
  float s = 0.f, s2 = 0.f;
  #pragma unroll
  for (int j = 0; j < 8; ++j) { float f = bf2f((uint16_t)v[j]); s += f; s2 += f * f; }
  #pragma unroll
  for (int o = 1; o < 64; o <<= 1) { s += __shfl_xor(s, o); s2 += __shfl_xor(s2, o); }
  if (lane == 0) {
    float mu  = s * (1.f / 512.f);
    float var = s2 * (1.f / 512.f) - mu * mu;
    float rs  = rsqrtf(var + 1e-5f);
    rstd_a[row] = rs;
    murs_a[row] = mu * rs;
  }
}

// ---------------------------------------------------------------------------
// u[n] = sum_k ln_b[k]*W1[n,k] + b1[n] ;  v[n] = sum_k ln_g[k]*W1[n,k]
// ---------------------------------------------------------------------------
__global__ void uv_kernel(const float* __restrict__ W1, const float* __restrict__ ln_g,
                          const float* __restrict__ ln_b, const float* __restrict__ b1,
                          float* __restrict__ u, float* __restrict__ v)
{
  const int lane = threadIdx.x & 63;
  const int row  = blockIdx.x * 4 + (threadIdx.x >> 6);
  const float* wp = W1 + (size_t)row * 512 + lane * 8;
  float4 w0 = *(const float4*)wp;
  float4 w1 = *(const float4*)(wp + 4);
  float4 g0 = *(const float4*)(ln_g + lane * 8);
  float4 g1 = *(const float4*)(ln_g + lane * 8 + 4);
  float4 b0 = *(const float4*)(ln_b + lane * 8);
  float4 b1v = *(const float4*)(ln_b + lane * 8 + 4);
  float su = b0.x * w0.x + b0.y * w0.y + b0.z * w0.z + b0.w * w0.w
           + b1v.x * w1.x + b1v.y * w1.y + b1v.z * w1.z + b1v.w * w1.w;
  float sv = g0.x * w0.x + g0.y * w0.y + g0.z * w0.z + g0.w * w0.w
           + g1.x * w1.x + g1.y * w1.y + g1.z * w1.z + g1.w * w1.w;
  #pragma unroll
  for (int o = 1; o < 64; o <<= 1) { su += __shfl_xor(su, o); sv += __shfl_xor(sv, o); }
  if (lane == 0) { u[row] = su + b1[row]; v[row] = sv; }
}

// ---------------------------------------------------------------------------
// Fused GEMM: C = tanh(epilogue(A[64 rows, K=512] @ W[,512]^T))
// MODE 0: LN-affine epilogue  tanh(rstd_m*G - murs_m*v_n + u_n)   (u has +b1)
// MODE 1: bias epilogue       tanh(G + bias_n)
// ---------------------------------------------------------------------------
template<int MODE>
__global__ __launch_bounds__(256, 2) void gemm_fused(
    const uint16_t* __restrict__ Abase, const uint16_t* __restrict__ W,
    uint16_t* __restrict__ C, int ntiles,
    const float* __restrict__ rstd_a, const float* __restrict__ murs_a,
    const float* __restrict__ uvec, const float* __restrict__ vvec,
    const float* __restrict__ bias)
{
  __shared__ uint16_t At[64 * 512];   // 65536 B
  const int tid  = threadIdx.x;
  const int lane = tid & 63;
  const int wv   = tid >> 6;
  const size_t mbase = (size_t)blockIdx.x * 64;

  for (int r8 = 0; r8 < 16; ++r8) {
    int row = wv * 16 + r8;
    int sb  = (lane * 16) ^ ((row & 7) << 4);
    gll16(Abase + (mbase + row) * 512 + sb / 2, At + row * 512);
  }
  __syncthreads();

  const int fr = lane & 15, kg = lane >> 4;
  const int mloc = (wv & 1) * 32;
  const int nhalf = (wv >> 1) * 64;

  for (int nt = 0; nt < ntiles; ++nt) {
    const int nbase = nt * 128 + nhalf;
    f32x4 vz = {0.f, 0.f, 0.f, 0.f};
    f32x4 acc[4][2];
    #pragma unroll
    for (int i = 0; i < 4; ++i) { acc[i][0] = vz; acc[i][1] = vz; }

    #pragma unroll 4
    for (int kb = 0; kb < 16; ++kb) {
      const int ke = kb * 32 + kg * 8;
      bf16x8 wf[4];
      #pragma unroll
      for (int i = 0; i < 4; ++i)
        wf[i] = *(const bf16x8*)(W + (size_t)(nbase + i * 16 + fr) * 512 + ke);
      bf16x8 af[2];
      #pragma unroll
      for (int j = 0; j < 2; ++j) {
        int mr = mloc + j * 16 + fr;
        af[j] = *(const bf16x8*)((const char*)At + ((mr * 1024 + ke * 2) ^ ((mr & 7) << 4)));
      }
      #pragma unroll
      for (int i = 0; i < 4; ++i)
        #pragma unroll
        for (int j = 0; j < 2; ++j)
          acc[i][j] = __builtin_amdgcn_mfma_f32_16x16x32_bf16(wf[i], af[j], acc[i][j], 0, 0, 0);
    }

    #pragma unroll
    for (int j = 0; j < 2; ++j) {
      size_t m = mbase + mloc + j * 16 + fr;
      float rs = 0.f, mrs = 0.f;
      if constexpr (MODE == 0) { rs = rstd_a[m]; mrs = murs_a[m]; }
      #pragma unroll
      for (int i = 0; i < 4; ++i) {
        int n = nbase + i * 16 + kg * 4;
        float o0, o1, o2, o3;
        if constexpr (MODE == 0) {
          float4 uu = *(const float4*)(uvec + n);
          float4 vv = *(const float4*)(vvec + n);
          o0 = tanh_fast(rs * acc[i][j][0] - mrs * vv.x + uu.x);
          o1 = tanh_fast(rs * acc[i][j][1] - mrs * vv.y + uu.y);
          o2 = tanh_fast(rs * acc[i][j][2] - mrs * vv.z + uu.z);
          o3 = tanh_fast(rs * acc[i][j][3] - mrs * vv.w + uu.w);
        } else {
          float4 bb = *(const float4*)(bias + n);
          o0 = tanh_fast(acc[i][j][0] + bb.x);
          o1 = tanh_fast(acc[i][j][1] + bb.y);
          o2 = tanh_fast(acc[i][j][2] + bb.z);
          o3 = tanh_fast(acc[i][j][3] + bb.w);
        }
        uint32_t lo = (uint32_t)f2bf(o0) | ((uint32_t)f2bf(o1) << 16);
        uint32_t hi = (uint32_t)f2bf(o2) | ((uint32_t)f2bf(o3) << 16);
        *(uint64_t*)(C + m * 512 + n) = (uint64_t)lo | ((uint64_t)hi << 32);
      }
    }
    __syncthreads();
  }
}

// ---------------------------------------------------------------------------
// value[m] = a2[m,:256] . Wv + bv   (a2 at stride 512; one wave per row)
// ---------------------------------------------------------------------------
__global__ void gemv_kernel(const uint16_t* __restrict__ a2, const float* __restrict__ Wv,
                            const float* __restrict__ bv, float* __restrict__ outv)
{
  const int lane = threadIdx.x & 63;
  const size_t row = (size_t)blockIdx.x * 4 + (threadIdx.x >> 6);
  const uint16_t* p = a2 + row * 512 + lane * 4;
  uint64_t v = *(const uint64_t*)p;
  float4 w = *(const float4*)(Wv + lane * 4);
  float d = bf2f((uint16_t)(v & 0xFFFF)) * w.x
          + bf2f((uint16_t)((v >> 16) & 0xFFFF)) * w.y
          + bf2f((uint16_t)((v >> 32) & 0xFFFF)) * w.z
          + bf2f((uint16_t)((v >> 48) & 0xFFFF)) * w.w;
  #pragma unroll
  for (int o = 1; o < 64; o <<= 1) d += __shfl_xor(d, o);
  if (lane == 0) outv[row] = d + bv[0];
}

// ---------------------------------------------------------------------------
// W1 (fold ln_g into columns) then W2, fp32 -> bf16 contiguous.
// ---------------------------------------------------------------------------
__global__ void wconv_kernel(const float* __restrict__ W1, const float* __restrict__ W2,
                             const float* __restrict__ ln_g, uint16_t* __restrict__ dst)
{
  int idx = blockIdx.x * 256 + threadIdx.x;
  int i4 = idx * 4;
  float4 v;
  if (i4 < 262144) {
    v = *(const float4*)(W1 + i4);
    int c = i4 & 511;
    float4 gv = *(const float4*)(ln_g + c);
    v.x *= gv.x; v.y *= gv.y; v.z *= gv.z; v.w *= gv.w;
  } else {
    v = *(const float4*)(W2 + (i4 - 262144));
  }
  uint32_t lo = (uint32_t)f2bf(v.x) | ((uint32_t)f2bf(v.y) << 16);
  uint32_t hi = (uint32_t)f2bf(v.z) | ((uint32_t)f2bf(v.w) << 16);
  *(uint64_t*)(dst + i4) = (uint64_t)lo | ((uint64_t)hi << 32);
}

extern "C" void kernel_launch(void* const* d_in, const int* in_sizes, int n_in,
                              void* d_out, int out_size, void* d_ws, size_t ws_size,
                              hipStream_t stream)
{
  (void)in_sizes; (void)n_in;
  const float* x    = (const float*)d_in[0];
  const float* done = (const float*)d_in[1];
  const float* h0   = (const float*)d_in[2];
  const float* c0   = (const float*)d_in[3];
  const float* W_ih = (const float*)d_in[4];
  const float* W_hh = (const float*)d_in[5];
  const float* b_ih = (const float*)d_in[6];
  const float* b_hh = (const float*)d_in[7];
  const float* ln_g = (const float*)d_in[8];
  const float* ln_b = (const float*)d_in[9];
  const float* W1   = (const float*)d_in[10];
  const float* b1   = (const float*)d_in[11];
  const float* W2   = (const float*)d_in[12];
  const float* b2   = (const float*)d_in[13];
  const float* Wv   = (const float*)d_in[14];
  const float* bv   = (const float*)d_in[15];
  float* out = (float*)d_out;
  char* ws = (char*)d_ws;

  // ws layout (bytes):
  //   0        flg      4096     (8 groups x 32 WG flags)
  //   4096     slotxcd  4096     (8 groups x 32 published XCD ids)
  //   8192     vslot    4096     (8 groups x 32 self-test verdicts)
  //   12288    tloc     4096     (1 test word per group)
  //   16384    wbf      786432   (bf16 W1g | W2)
  //   802816   u,v      4096     (512 f32 each)
  //   806912   rstd     524288
  //   1331200  murs     524288
  //   2097152  hs       134217728  (bf16 [T*B,512]; later a1 in-place, a2 cols 0..255)
  constexpr size_t NEED = 2097152ULL + 134217728ULL;
  if (ws_size < NEED) {
    hipMemsetAsync(d_out, 0, (size_t)out_size * 4, stream);
    return;
  }
  uint32_t* flg  = (uint32_t*)ws;
  uint32_t* sxc  = (uint32_t*)(ws + 4096);
  uint32_t* vsl  = (uint32_t*)(ws + 8192);
  uint32_t* tlc  = (uint32_t*)(ws + 12288);
  uint16_t* wbf  = (uint16_t*)(ws + 16384);
  float*    uv_u = (float*)(ws + 802816);
  float*    uv_v = (float*)(ws + 802816 + 2048);
  float*    rstd = (float*)(ws + 806912);
  float*    murs = (float*)(ws + 1331200);
  uint16_t* hsb  = (uint16_t*)(ws + 2097152);

  hipMemsetAsync(ws, 0, 16384, stream);
  hipLaunchKernelGGL(wconv_kernel, dim3(384), dim3(256), 0, stream, W1, W2, ln_g, wbf);
  hipLaunchKernelGGL(uv_kernel, dim3(128), dim3(256), 0, stream, W1, ln_g, ln_b, b1, uv_u, uv_v);
  hipLaunchKernelGGL(lstm_kernel, dim3(256), dim3(256), 0, stream,
                     x, done, h0, c0, W_ih, W_hh, b_ih, b_hh, hsb, flg, sxc, vsl, tlc, out);
  hipLaunchKernelGGL(ln_stats_kernel, dim3(32768), dim3(256), 0, stream, hsb, rstd, murs);
  // GEMM1: a1 = tanh(LN(h) @ W1^T + b1), in-place over hs
  hipLaunchKernelGGL((gemm_fused<0>), dim3(2048), dim3(256), 0, stream,
                     hsb, wbf, hsb, 4, rstd, murs, uv_u, uv_v, (const float*)nullptr);
  // GEMM2: a2 = tanh(a1 @ W2^T + b2), in-place over hs cols [0,256)
  hipLaunchKernelGGL((gemm_fused<1>), dim3(2048), dim3(256), 0, stream,
                     hsb, wbf + 262144, hsb, 2,
                     (const float*)nullptr, (const float*)nullptr,
                     (const float*)nullptr, (const float*)nullptr, b2);
  hipLaunchKernelGGL(gemv_kernel, dim3(32768), dim3(256), 0, stream, hsb, Wv, bv, out);
}

// Round 9
// 6517.088 us; speedup vs baseline: 1.0051x; 1.0051x over previous
//
#include <hip/hip_runtime.h>
#include <stdint.h>

// Problem constants
constexpr int T_STEPS = 512;
constexpr int BSZ     = 256;
constexpr int OBSD    = 64;
constexpr int HID     = 512;
constexpr int NROWS   = T_STEPS * BSZ;   // 131072

// LSTM partitioning: 8 groups x 32 WGs; group owns 32 batch rows; WG owns 16 h-cols
// group = wg & 7 -> under round-robin dispatch all members land on one XCD.
constexpr int GROUPS = 8;
constexpr int WPG    = 32;
constexpr int BW     = 32;
constexpr int TEST_BUDGET = 50000;

typedef __attribute__((ext_vector_type(8))) short bf16x8;
typedef __attribute__((ext_vector_type(4))) float f32x4;

__device__ __forceinline__ float bf2f(uint16_t u) {
  union { uint32_t i; float f; } v; v.i = ((uint32_t)u) << 16; return v.f;
}
__device__ __forceinline__ uint16_t f2bf(float f) {
  union { float f; uint32_t i; } v; v.f = f;
  return (uint16_t)((v.i + 0x7FFFu + ((v.i >> 16) & 1u)) >> 16);
}
__device__ __forceinline__ uint64_t pack4(float a, float b, float c, float d) {
  uint32_t lo = (uint32_t)f2bf(a) | ((uint32_t)f2bf(b) << 16);
  uint32_t hi = (uint32_t)f2bf(c) | ((uint32_t)f2bf(d) << 16);
  return (uint64_t)lo | ((uint64_t)hi << 32);
}
__device__ __forceinline__ float sigm(float x) { return 1.f / (1.f + __expf(-x)); }
__device__ __forceinline__ float tanh_fast(float x) {
  float e = __expf(2.f * x);
  return 1.f - 2.f / (e + 1.f);
}

__device__ __forceinline__ void gll16(const void* g, void* l) {
  __builtin_amdgcn_global_load_lds(
      (const __attribute__((address_space(1))) uint32_t*)g,
      (__attribute__((address_space(3))) uint32_t*)l, 16, 0, 0);
}

// sc0-scoped store: write-through to the XCD-shared L2 (the fast-path
// coherence point). Plain stores ACK at the CU write-combine buffer and
// drain lazily (round-8 finding: ~7us/step visibility stall); sc0 forces
// prompt visibility to same-XCD sc0 readers.
__device__ __forceinline__ void store_sc0(uint32_t* p, uint32_t v) {
  asm volatile("global_store_dword %0, %1, off sc0" :: "v"(p), "v"(v) : "memory");
}

// ---------------------------------------------------------------------------
// Persistent LSTM scan. 256 blocks x 256 threads, 1 block/CU.
// SLOW path == round-5 protocol (proven): agent-scope (LIC) h/flag traffic.
// FAST path (XCD-L2 transport, validated each launch by a bounded self-test):
//   sc0 stores (write-through to XCD L2) + sc0 loads (L1-bypass, L2-served).
// Poll discipline: only wave 0 polls, s_sleep(1) backoff, barrier releases.
// MFMA partition: wave = 2 gates x 16 rows -> 18 ds_read_b128/wave.
// ---------------------------------------------------------------------------
__global__ __launch_bounds__(256, 1) void lstm_kernel(
    const float* __restrict__ xin, const float* __restrict__ done,
    const float* __restrict__ h0, const float* __restrict__ c0,
    const float* __restrict__ W_ih, const float* __restrict__ W_hh,
    const float* __restrict__ b_ih, const float* __restrict__ b_hh,
    uint16_t* __restrict__ hs, uint32_t* __restrict__ flg,
    uint32_t* __restrict__ slotxcd, uint32_t* __restrict__ vslot,
    uint32_t* __restrict__ tloc, float* __restrict__ out)
{
  __shared__ char  Ab[32 * 1152];
  __shared__ float gl[4 * 544];     // [gate][32 rows][17 pad]
  __shared__ float bl[64];
  __shared__ int   s_fast;

  const int wg   = blockIdx.x;
  const int g    = wg & 7;          // group == presumed XCD
  const int win  = wg >> 3;         // slot within group: h-col slice
  const int bg   = g * BW;
  const int tid  = threadIdx.x;
  const int lane = tid & 63;
  const int q    = tid >> 6;        // wave id

  // one-time: drop any stale L1/L2 lines from a previous graph replay
  __builtin_amdgcn_fence(__ATOMIC_ACQUIRE, "agent");

  // ---- publish my XCD id (proven agent path) ----
  uint32_t xcd;
  asm volatile("s_getreg_b32 %0, hwreg(HW_REG_XCC_ID)" : "=s"(xcd));
  if (tid == 0)
    __hip_atomic_store(slotxcd + g * 32 + win, xcd | 0x100u,
                       __ATOMIC_RELAXED, __HIP_MEMORY_SCOPE_AGENT);

  // ---- one-time: weight fragments into VGPRs. wave q: gates gp, gp+1 ----
  const int gp   = (q >> 1) * 2;    // gate pair base
  const int rblk = (q & 1) * 16;    // row block for MFMA
  bf16x8 bqA[18], bqB[18];
  {
    const int rowA = gp * 512 + win * 16 + (lane & 15);
    const int rowB = (gp + 1) * 512 + win * 16 + (lane & 15);
    const int kg8  = (lane >> 4) * 8;
    #pragma unroll
    for (int ks = 0; ks < 18; ++ks) {
      const float* srcA = (ks < 16)
          ? (W_hh + (size_t)rowA * 512 + ks * 32 + kg8)
          : (W_ih + (size_t)rowA * 64 + (ks - 16) * 32 + kg8);
      const float* srcB = (ks < 16)
          ? (W_hh + (size_t)rowB * 512 + ks * 32 + kg8)
          : (W_ih + (size_t)rowB * 64 + (ks - 16) * 32 + kg8);
      float4 a0 = *(const float4*)srcA;
      float4 a1 = *(const float4*)(srcA + 4);
      float4 b0 = *(const float4*)srcB;
      float4 b1 = *(const float4*)(srcB + 4);
      bf16x8 va, vb;
      va[0] = (short)f2bf(a0.x); va[1] = (short)f2bf(a0.y);
      va[2] = (short)f2bf(a0.z); va[3] = (short)f2bf(a0.w);
      va[4] = (short)f2bf(a1.x); va[5] = (short)f2bf(a1.y);
      va[6] = (short)f2bf(a1.z); va[7] = (short)f2bf(a1.w);
      vb[0] = (short)f2bf(b0.x); vb[1] = (short)f2bf(b0.y);
      vb[2] = (short)f2bf(b0.z); vb[3] = (short)f2bf(b0.w);
      vb[4] = (short)f2bf(b1.x); vb[5] = (short)f2bf(b1.y);
      vb[6] = (short)f2bf(b1.z); vb[7] = (short)f2bf(b1.w);
      bqA[ks] = va; bqB[ks] = vb;
    }
  }
  if (tid < 64) {
    int q2 = tid >> 4, c = tid & 15;
    int grow = q2 * 512 + win * 16 + c;
    bl[tid] = b_ih[grow] + b_hh[grow];
  }

  // ---- wave 0: cleanliness collect + hardware self-test + verdict ----
  // Self-test now exercises the EXACT steady-state ops: sc0 store -> sc0 load.
  if (q == 0) {
    uint32_t v = 0;
    if (lane < WPG) {
      for (;;) {
        v = __hip_atomic_load(slotxcd + g * 32 + lane,
                              __ATOMIC_RELAXED, __HIP_MEMORY_SCOPE_AGENT);
        if (v != 0) break;
        __builtin_amdgcn_s_sleep(1);
      }
    }
    bool alleq = __all((int)((lane < WPG) ? (v == (xcd | 0x100u)) : 1));

    int pass = 0;
    if (alleq) {
      if (win == 0 && lane == 0) {
        for (int d = 0; d < 100; ++d) __builtin_amdgcn_s_sleep(4);
        store_sc0(tloc + g, 1u);
        asm volatile("s_waitcnt vmcnt(0)" ::: "memory");
        for (int d = 0; d < 100; ++d) __builtin_amdgcn_s_sleep(4);
        store_sc0(tloc + g, 2u);
        asm volatile("s_waitcnt vmcnt(0)" ::: "memory");
      }
      bool p1 = false, p2 = false;
      for (int it = 0; it < TEST_BUDGET; ++it) {
        uint32_t tv;
        asm volatile("global_load_dword %0, %1, off sc0\n\ts_waitcnt vmcnt(0)"
                     : "=v"(tv) : "v"(tloc + g) : "memory");
        if (tv >= 1u) { p1 = true; break; }
      }
      if (p1) {
        for (int it = 0; it < TEST_BUDGET; ++it) {
          uint32_t tv;
          asm volatile("global_load_dword %0, %1, off sc0\n\ts_waitcnt vmcnt(0)"
                       : "=v"(tv) : "v"(tloc + g) : "memory");
          if (tv >= 2u) { p2 = true; break; }
        }
      }
      pass = (p1 && p2) ? 1 : 0;
    }
    if (lane == 0)
      __hip_atomic_store(vslot + g * 32 + win, pass ? 2u : 1u,
                         __ATOMIC_RELAXED, __HIP_MEMORY_SCOPE_AGENT);
    uint32_t pv = 0;
    if (lane < WPG) {
      for (;;) {
        pv = __hip_atomic_load(vslot + g * 32 + lane,
                               __ATOMIC_RELAXED, __HIP_MEMORY_SCOPE_AGENT);
        if (pv != 0) break;
        __builtin_amdgcn_s_sleep(1);
      }
    }
    bool allpass = __all((int)((lane < WPG) ? (pv == 2u) : 1));
    if (lane == 0) s_fast = allpass ? 1 : 0;
  }

  const int b_loc = tid >> 3;        // 0..31 (batch row within group)
  const int n0    = (tid & 7) * 2;   // h-col pair within WG's 16 cols
  float creg0 = c0[(size_t)(bg + b_loc) * HID + win * 16 + n0];
  float creg1 = c0[(size_t)(bg + b_loc) * HID + win * 16 + n0 + 1];

  const int sr  = tid >> 3;          // x staging row
  const int sc8 = (tid & 7) * 8;     // x col base
  const int rw  = q * 8;             // wave's h staging rows

  __syncthreads();
  const bool fast = (s_fast != 0);

  for (int t = 0; t < T_STEPS; ++t) {
    // ---- hoisted loads (overlap the poll): x_t, done values ----
    const float* xp = xin + ((size_t)t * BSZ + bg + sr) * OBSD + sc8;
    float4 xa = *(const float4*)xp;
    float4 xb = *(const float4*)(xp + 4);
    float dvs[8];
    #pragma unroll
    for (int r8 = 0; r8 < 8; ++r8)
      dvs[r8] = done[(size_t)t * BSZ + bg + rw + r8];
    float dv_b = done[(size_t)t * BSZ + bg + b_loc];

    // stage x_t into Ab (end-of-prev-step barrier -> no race with MFMA)
    {
      uint4 u4;
      u4.x = (uint32_t)f2bf(xa.x) | ((uint32_t)f2bf(xa.y) << 16);
      u4.y = (uint32_t)f2bf(xa.z) | ((uint32_t)f2bf(xa.w) << 16);
      u4.z = (uint32_t)f2bf(xb.x) | ((uint32_t)f2bf(xb.y) << 16);
      u4.w = (uint32_t)f2bf(xb.z) | ((uint32_t)f2bf(xb.w) << 16);
      *(uint4*)(Ab + ((sr * 1152 + 1024 + sc8 * 2) ^ ((sr & 7) << 4))) = u4;
    }

    // ---- wave 0 polls group flags (throttled); barrier releases the rest ----
    if (t > 0) {
      if (q == 0) {
        if (fast) {
          for (;;) {
            uint32_t f = 0xFFFFFFFFu;
            if (lane < WPG) {
              asm volatile("global_load_dword %0, %1, off sc0\n\ts_waitcnt vmcnt(0)"
                           : "=v"(f) : "v"(flg + g * 32 + lane) : "memory");
            }
            if (__all((int)(f >= (uint32_t)t))) break;
            __builtin_amdgcn_s_sleep(1);
          }
        } else {
          for (;;) {
            uint32_t f = (lane < WPG)
                ? __hip_atomic_load(flg + g * 32 + lane, __ATOMIC_RELAXED, __HIP_MEMORY_SCOPE_AGENT)
                : 0xFFFFFFFFu;
            if (__all((int)(f >= (uint32_t)t))) break;
            __builtin_amdgcn_s_sleep(1);
          }
        }
        __builtin_amdgcn_fence(__ATOMIC_ACQUIRE, "workgroup");
      }
      __syncthreads();
    }

    // ---- stage h_{t-1}: wave loads its 8 rows, coalesced 512B per instr ----
    if (t == 0) {
      #pragma unroll
      for (int r8 = 0; r8 < 8; ++r8) {
        int r = rw + r8;
        uint64_t v0 = 0, v1 = 0;
        if (dvs[r8] <= 0.5f) {
          const float* hp = h0 + (size_t)(bg + r) * HID;
          float4 ha = *(const float4*)(hp + lane * 4);
          float4 hb = *(const float4*)(hp + 256 + lane * 4);
          v0 = pack4(ha.x, ha.y, ha.z, ha.w);
          v1 = pack4(hb.x, hb.y, hb.z, hb.w);
        }
        *(uint64_t*)(Ab + ((r * 1152 + lane * 8) ^ ((r & 7) << 4))) = v0;
        *(uint64_t*)(Ab + ((r * 1152 + 512 + lane * 8) ^ ((r & 7) << 4))) = v1;
      }
    } else if (fast) {
      // FAST: sc0 loads served by the XCD-shared L2
      uint64_t hv0[8], hv1[8];
      const uint64_t* hb = (const uint64_t*)hs + ((size_t)(t - 1) * BSZ + bg) * 128;
      #pragma unroll
      for (int r8 = 0; r8 < 8; ++r8) {
        const uint64_t* hrow = hb + (size_t)(rw + r8) * 128;
        asm volatile("global_load_dwordx2 %0, %1, off sc0"
                     : "=v"(hv0[r8]) : "v"(hrow + lane));
        asm volatile("global_load_dwordx2 %0, %1, off sc0"
                     : "=v"(hv1[r8]) : "v"(hrow + 64 + lane));
      }
      asm volatile("s_waitcnt vmcnt(0)" ::: "memory");
      __builtin_amdgcn_sched_barrier(0);
      #pragma unroll
      for (int r8 = 0; r8 < 8; ++r8) {
        int r = rw + r8;
        uint64_t v0 = hv0[r8], v1 = hv1[r8];
        if (dvs[r8] > 0.5f) { v0 = 0; v1 = 0; }
        *(uint64_t*)(Ab + ((r * 1152 + lane * 8) ^ ((r & 7) << 4))) = v0;
        *(uint64_t*)(Ab + ((r * 1152 + 512 + lane * 8) ^ ((r & 7) << 4))) = v1;
      }
    } else {
      // SLOW: agent-scope (LIC) loads -- round-5 path
      #pragma unroll
      for (int r8 = 0; r8 < 8; ++r8) {
        int r = rw + r8;
        const uint64_t* hrow =
            (const uint64_t*)hs + ((size_t)(t - 1) * BSZ + bg + r) * 128;
        uint64_t v0 = __hip_atomic_load(hrow + lane, __ATOMIC_RELAXED, __HIP_MEMORY_SCOPE_AGENT);
        uint64_t v1 = __hip_atomic_load(hrow + 64 + lane, __ATOMIC_RELAXED, __HIP_MEMORY_SCOPE_AGENT);
        if (dvs[r8] > 0.5f) { v0 = 0; v1 = 0; }
        *(uint64_t*)(Ab + ((r * 1152 + lane * 8) ^ ((r & 7) << 4))) = v0;
        *(uint64_t*)(Ab + ((r * 1152 + 512 + lane * 8) ^ ((r & 7) << 4))) = v1;
      }
    }
    __syncthreads();

    // ---- MFMA: wave computes [16 rows x 16 cols] for gates gp and gp+1 ----
    f32x4 ac0 = {0.f, 0.f, 0.f, 0.f};
    f32x4 ac1 = {0.f, 0.f, 0.f, 0.f};
    {
      const int ar = rblk + (lane & 15);
      const int kg = lane >> 4;
      #pragma unroll
      for (int ks = 0; ks < 18; ++ks) {
        int kb = (ks * 32 + kg * 8) * 2;
        bf16x8 a = *(const bf16x8*)(Ab + ((ar * 1152 + kb) ^ ((ar & 7) << 4)));
        ac0 = __builtin_amdgcn_mfma_f32_16x16x32_bf16(a, bqA[ks], ac0, 0, 0, 0);
        ac1 = __builtin_amdgcn_mfma_f32_16x16x32_bf16(a, bqB[ks], ac1, 0, 0, 0);
      }
    }
    // ---- gates -> LDS exchange (rows padded to 17 words) ----
    {
      int c  = lane & 15;
      int rb = rblk + (lane >> 4) * 4;
      #pragma unroll
      for (int r = 0; r < 4; ++r) {
        gl[gp * 544 + (rb + r) * 17 + c]       = ac0[r];
        gl[(gp + 1) * 544 + (rb + r) * 17 + c] = ac1[r];
      }
    }
    __syncthreads();
    // ---- cell update (c lives in registers across all 512 steps) ----
    {
      float m = dv_b > 0.5f ? 0.f : 1.f;
      float h0v, h1v;
      {
        float I = gl[b_loc * 17 + n0]         + bl[n0];
        float F = gl[544 + b_loc * 17 + n0]   + bl[16 + n0];
        float G = gl[1088 + b_loc * 17 + n0]  + bl[32 + n0];
        float O = gl[1632 + b_loc * 17 + n0]  + bl[48 + n0];
        float cc = creg0 * m;
        cc = sigm(F) * cc + sigm(I) * tanh_fast(G);
        creg0 = cc;
        h0v = sigm(O) * tanh_fast(cc);
      }
      {
        int n1 = n0 + 1;
        float I = gl[b_loc * 17 + n1]         + bl[n1];
        float F = gl[544 + b_loc * 17 + n1]   + bl[16 + n1];
        float G = gl[1088 + b_loc * 17 + n1]  + bl[32 + n1];
        float O = gl[1632 + b_loc * 17 + n1]  + bl[48 + n1];
        float cc = creg1 * m;
        cc = sigm(F) * cc + sigm(I) * tanh_fast(G);
        creg1 = cc;
        h1v = sigm(O) * tanh_fast(cc);
      }
      uint32_t pk = (uint32_t)f2bf(h0v) | ((uint32_t)f2bf(h1v) << 16);
      uint32_t* hp = (uint32_t*)(hs + ((size_t)t * BSZ + bg + b_loc) * HID + win * 16 + n0);
      if (fast)   // sc0 store: prompt write-through to the XCD L2
        store_sc0(hp, pk);
      else        // agent-scope: LIC (round-5 path)
        __hip_atomic_store(hp, pk, __ATOMIC_RELAXED, __HIP_MEMORY_SCOPE_AGENT);
      if (t == T_STEPS - 1) {
        size_t ob = (size_t)(bg + b_loc) * HID + win * 16 + n0;
        out[NROWS + ob]         = h0v;
        out[NROWS + ob + 1]     = h1v;
        out[2 * NROWS + ob]     = creg0;
        out[2 * NROWS + ob + 1] = creg1;
      }
    }
    __syncthreads();   // per-wave vmcnt(0) drain -> h stores ACKed at L2/LIC
    if (tid == 0) {
      if (fast)
        store_sc0(flg + g * 32 + win, (uint32_t)(t + 1));
      else
        __hip_atomic_store(flg + g * 32 + win, (uint32_t)(t + 1),
                           __ATOMIC_RELAXED, __HIP_MEMORY_SCOPE_AGENT);
    }
  }
}

// ---------------------------------------------------------------------------
// Per-row LayerNorm stats from bf16 hidden: rstd[m], murs[m] = mu*rstd.
// ---------------------------------------------------------------------------
__global__ void ln_stats_kernel(const uint16_t* __restrict__ hsrc,
                                float* __restrict__ rstd_a, float* __restrict__ murs_a)
{
  const int lane = threadIdx.x & 63;
  const size_t row = (size_t)blockIdx.x * 4 + (threadIdx.x >> 6);
  bf16x8 v = *(const bf16x8*)(hsrc + row * 512 + lane * 8);
  float s = 0.f, s2 = 0.f;
  #pragma unroll
  for (int j = 0; j < 8; ++j) { float f = bf2f((uint16_t)v[j]); s += f; s2 += f * f; }
  #pragma unroll
  for (int o = 1; o < 64; o <<= 1) { s += __shfl_xor(s, o); s2 += __shfl_xor(s2, o); }
  if (lane == 0) {
    float mu  = s * (1.f / 512.f);
    float var = s2 * (1.f / 512.f) - mu * mu;
    float rs  = rsqrtf(var + 1e-5f);
    rstd_a[row] = rs;
    murs_a[row] = mu * rs;
  }
}

// ---------------------------------------------------------------------------
// u[n] = sum_k ln_b[k]*W1[n,k] + b1[n] ;  v[n] = sum_k ln_g[k]*W1[n,k]
// ---------------------------------------------------------------------------
__global__ void uv_kernel(const float* __restrict__ W1, const float* __restrict__ ln_g,
                          const float* __restrict__ ln_b, const float* __restrict__ b1,
                          float* __restrict__ u, float* __restrict__ v)
{
  const int lane = threadIdx.x & 63;
  const int row  = blockIdx.x * 4 + (threadIdx.x >> 6);
  const float* wp = W1 + (size_t)row * 512 + lane * 8;
  float4 w0 = *(const float4*)wp;
  float4 w1 = *(const float4*)(wp + 4);
  float4 g0 = *(const float4*)(ln_g + lane * 8);
  float4 g1 = *(const float4*)(ln_g + lane * 8 + 4);
  float4 b0 = *(const float4*)(ln_b + lane * 8);
  float4 b1v = *(const float4*)(ln_b + lane * 8 + 4);
  float su = b0.x * w0.x + b0.y * w0.y + b0.z * w0.z + b0.w * w0.w
           + b1v.x * w1.x + b1v.y * w1.y + b1v.z * w1.z + b1v.w * w1.w;
  float sv = g0.x * w0.x + g0.y * w0.y + g0.z * w0.z + g0.w * w0.w
           + g1.x * w1.x + g1.y * w1.y + g1.z * w1.z + g1.w * w1.w;
  #pragma unroll
  for (int o = 1; o < 64; o <<= 1) { su += __shfl_xor(su, o); sv += __shfl_xor(sv, o); }
  if (lane == 0) { u[row] = su + b1[row]; v[row] = sv; }
}

// ---------------------------------------------------------------------------
// Fused GEMM: C = tanh(epilogue(A[64 rows, K=512] @ W[,512]^T))
// MODE 0: LN-affine epilogue  tanh(rstd_m*G - murs_m*v_n + u_n)   (u has +b1)
// MODE 1: bias epilogue       tanh(G + bias_n)
// ---------------------------------------------------------------------------
template<int MODE>
__global__ __launch_bounds__(256, 2) void gemm_fused(
    const uint16_t* __restrict__ Abase, const uint16_t* __restrict__ W,
    uint16_t* __restrict__ C, int ntiles,
    const float* __restrict__ rstd_a, const float* __restrict__ murs_a,
    const float* __restrict__ uvec, const float* __restrict__ vvec,
    const float* __restrict__ bias)
{
  __shared__ uint16_t At[64 * 512];   // 65536 B
  const int tid  = threadIdx.x;
  const int lane = tid & 63;
  const int wv   = tid >> 6;
  const size_t mbase = (size_t)blockIdx.x * 64;

  for (int r8 = 0; r8 < 16; ++r8) {
    int row = wv * 16 + r8;
    int sb  = (lane * 16) ^ ((row & 7) << 4);
    gll16(Abase + (mbase + row) * 512 + sb / 2, At + row * 512);
  }
  __syncthreads();

  const int fr = lane & 15, kg = lane >> 4;
  const int mloc = (wv & 1) * 32;
  const int nhalf = (wv >> 1) * 64;

  for (int nt = 0; nt < ntiles; ++nt) {
    const int nbase = nt * 128 + nhalf;
    f32x4 vz = {0.f, 0.f, 0.f, 0.f};
    f32x4 acc[4][2];
    #pragma unroll
    for (int i = 0; i < 4; ++i) { acc[i][0] = vz; acc[i][1] = vz; }

    #pragma unroll 4
    for (int kb = 0; kb < 16; ++kb) {
      const int ke = kb * 32 + kg * 8;
      bf16x8 wf[4];
      #pragma unroll
      for (int i = 0; i < 4; ++i)
        wf[i] = *(const bf16x8*)(W + (size_t)(nbase + i * 16 + fr) * 512 + ke);
      bf16x8 af[2];
      #pragma unroll
      for (int j = 0; j < 2; ++j) {
        int mr = mloc + j * 16 + fr;
        af[j] = *(const bf16x8*)((const char*)At + ((mr * 1024 + ke * 2) ^ ((mr & 7) << 4)));
      }
      #pragma unroll
      for (int i = 0; i < 4; ++i)
        #pragma unroll
        for (int j = 0; j < 2; ++j)
          acc[i][j] = __builtin_amdgcn_mfma_f32_16x16x32_bf16(wf[i], af[j], acc[i][j], 0, 0, 0);
    }

    #pragma unroll
    for (int j = 0; j < 2; ++j) {
      size_t m = mbase + mloc + j * 16 + fr;
      float rs = 0.f, mrs = 0.f;
      if constexpr (MODE == 0) { rs = rstd_a[m]; mrs = murs_a[m]; }
      #pragma unroll
      for (int i = 0; i < 4; ++i) {
        int n = nbase + i * 16 + kg * 4;
        float o0, o1, o2, o3;
        if constexpr (MODE == 0) {
          float4 uu = *(const float4*)(uvec + n);
          float4 vv = *(const float4*)(vvec + n);
          o0 = tanh_fast(rs * acc[i][j][0] - mrs * vv.x + uu.x);
          o1 = tanh_fast(rs * acc[i][j][1] - mrs * vv.y + uu.y);
          o2 = tanh_fast(rs * acc[i][j][2] - mrs * vv.z + uu.z);
          o3 = tanh_fast(rs * acc[i][j][3] - mrs * vv.w + uu.w);
        } else {
          float4 bb = *(const float4*)(bias + n);
          o0 = tanh_fast(acc[i][j][0] + bb.x);
          o1 = tanh_fast(acc[i][j][1] + bb.y);
          o2 = tanh_fast(acc[i][j][2] + bb.z);
          o3 = tanh_fast(acc[i][j][3] + bb.w);
        }
        uint32_t lo = (uint32_t)f2bf(o0) | ((uint32_t)f2bf(o1) << 16);
        uint32_t hi = (uint32_t)f2bf(o2) | ((uint32_t)f2bf(o3) << 16);
        *(uint64_t*)(C + m * 512 + n) = (uint64_t)lo | ((uint64_t)hi << 32);
      }
    }
    __syncthreads();
  }
}

// ---------------------------------------------------------------------------
// value[m] = a2[m,:256] . Wv + bv   (a2 at stride 512; one wave per row)
// ---------------------------------------------------------------------------
__global__ void gemv_kernel(const uint16_t* __restrict__ a2, const float* __restrict__ Wv,
                            const float* __restrict__ bv, float* __restrict__ outv)
{
  const int lane = threadIdx.x & 63;
  const size_t row = (size_t)blockIdx.x * 4 + (threadIdx.x >> 6);
  const uint16_t* p = a2 + row * 512 + lane * 4;
  uint64_t v = *(const uint64_t*)p;
  float4 w = *(const float4*)(Wv + lane * 4);
  float d = bf2f((uint16_t)(v & 0xFFFF)) * w.x
          + bf2f((uint16_t)((v >> 16) & 0xFFFF)) * w.y
          + bf2f((uint16_t)((v >> 32) & 0xFFFF)) * w.z
          + bf2f((uint16_t)((v >> 48) & 0xFFFF)) * w.w;
  #pragma unroll
  for (int o = 1; o < 64; o <<= 1) d += __shfl_xor(d, o);
  if (lane == 0) outv[row] = d + bv[0];
}

// ---------------------------------------------------------------------------
// W1 (fold ln_g into columns) then W2, fp32 -> bf16 contiguous.
// ---------------------------------------------------------------------------
__global__ void wconv_kernel(const float* __restrict__ W1, const float* __restrict__ W2,
                             const float* __restrict__ ln_g, uint16_t* __restrict__ dst)
{
  int idx = blockIdx.x * 256 + threadIdx.x;
  int i4 = idx * 4;
  float4 v;
  if (i4 < 262144) {
    v = *(const float4*)(W1 + i4);
    int c = i4 & 511;
    float4 gv = *(const float4*)(ln_g + c);
    v.x *= gv.x; v.y *= gv.y; v.z *= gv.z; v.w *= gv.w;
  } else {
    v = *(const float4*)(W2 + (i4 - 262144));
  }
  uint32_t lo = (uint32_t)f2bf(v.x) | ((uint32_t)f2bf(v.y) << 16);
  uint32_t hi = (uint32_t)f2bf(v.z) | ((uint32_t)f2bf(v.w) << 16);
  *(uint64_t*)(dst + i4) = (uint64_t)lo | ((uint64_t)hi << 32);
}

extern "C" void kernel_launch(void* const* d_in, const int* in_sizes, int n_in,
                              void* d_out, int out_size, void* d_ws, size_t ws_size,
                              hipStream_t stream)
{
  (void)in_sizes; (void)n_in;
  const float* x    = (const float*)d_in[0];
  const float* done = (const float*)d_in[1];
  const float* h0   = (const float*)d_in[2];
  const float* c0   = (const float*)d_in[3];
  const float* W_ih = (const float*)d_in[4];
  const float* W_hh = (const float*)d_in[5];
  const float* b_ih = (const float*)d_in[6];
  const float* b_hh = (const float*)d_in[7];
  const float* ln_g = (const float*)d_in[8];
  const float* ln_b = (const float*)d_in[9];
  const float* W1   = (const float*)d_in[10];
  const float* b1   = (const float*)d_in[11];
  const float* W2   = (const float*)d_in[12];
  const float* b2   = (const float*)d_in[13];
  const float* Wv   = (const float*)d_in[14];
  const float* bv   = (const float*)d_in[15];
  float* out = (float*)d_out;
  char* ws = (char*)d_ws;

  // ws layout (bytes):
  //   0        flg      4096     (8 groups x 32 WG flags)
  //   4096     slotxcd  4096     (8 groups x 32 published XCD ids)
  //   8192     vslot    4096     (8 groups x 32 self-test verdicts)
  //   12288    tloc     4096     (1 test word per group)
  //   16384    wbf      786432   (bf16 W1g | W2)
  //   802816   u,v      4096     (512 f32 each)
  //   806912   rstd     524288
  //   1331200  murs     524288
  //   2097152  hs       134217728  (bf16 [T*B,512]; later a1 in-place, a2 cols 0..255)
  constexpr size_t NEED = 2097152ULL + 134217728ULL;
  if (ws_size < NEED) {
    hipMemsetAsync(d_out, 0, (size_t)out_size * 4, stream);
    return;
  }
  uint32_t* flg  = (uint32_t*)ws;
  uint32_t* sxc  = (uint32_t*)(ws + 4096);
  uint32_t* vsl  = (uint32_t*)(ws + 8192);
  uint32_t* tlc  = (uint32_t*)(ws + 12288);
  uint16_t* wbf  = (uint16_t*)(ws + 16384);
  float*    uv_u = (float*)(ws + 802816);
  float*    uv_v = (float*)(ws + 802816 + 2048);
  float*    rstd = (float*)(ws + 806912);
  float*    murs = (float*)(ws + 1331200);
  uint16_t* hsb  = (uint16_t*)(ws + 2097152);

  hipMemsetAsync(ws, 0, 16384, stream);
  hipLaunchKernelGGL(wconv_kernel, dim3(384), dim3(256), 0, stream, W1, W2, ln_g, wbf);
  hipLaunchKernelGGL(uv_kernel, dim3(128), dim3(256), 0, stream, W1, ln_g, ln_b, b1, uv_u, uv_v);
  hipLaunchKernelGGL(lstm_kernel, dim3(256), dim3(256), 0, stream,
                     x, done, h0, c0, W_ih, W_hh, b_ih, b_hh, hsb, flg, sxc, vsl, tlc, out);
  hipLaunchKernelGGL(ln_stats_kernel, dim3(32768), dim3(256), 0, stream, hsb, rstd, murs);
  // GEMM1: a1 = tanh(LN(h) @ W1^T + b1), in-place over hs
  hipLaunchKernelGGL((gemm_fused<0>), dim3(2048), dim3(256), 0, stream,
                     hsb, wbf, hsb, 4, rstd, murs, uv_u, uv_v, (const float*)nullptr);
  // GEMM2: a2 = tanh(a1 @ W2^T + b2), in-place over hs cols [0,256)
  hipLaunchKernelGGL((gemm_fused<1>), dim3(2048), dim3(256), 0, stream,
                     hsb, wbf + 262144, hsb, 2,
                     (const float*)nullptr, (const float*)nullptr,
                     (const float*)nullptr, (const float*)nullptr, b2);
  hipLaunchKernelGGL(gemv_kernel, dim3(32768), dim3(256), 0, stream, hsb, Wv, bv, out);
}

// Round 10
// 2336.521 us; speedup vs baseline: 2.8036x; 2.7892x over previous
//
#include <hip/hip_runtime.h>
#include <stdint.h>

// Problem constants
constexpr int T_STEPS = 512;
constexpr int BSZ     = 256;
constexpr int OBSD    = 64;
constexpr int HID     = 512;
constexpr int NROWS   = T_STEPS * BSZ;   // 131072

// LSTM partitioning: 16 groups x 16 WGs. Group owns 16 batch rows; WG owns
// 32 h-cols (all 4 gates). Halves LIC read amplification + straggler pool
// vs the 8x32 partition (round-5 -> round-10 change).
constexpr int GROUPS = 16;
constexpr int WPG    = 16;
constexpr int BW     = 16;

typedef __attribute__((ext_vector_type(8))) short bf16x8;
typedef __attribute__((ext_vector_type(4))) float f32x4;

__device__ __forceinline__ float bf2f(uint16_t u) {
  union { uint32_t i; float f; } v; v.i = ((uint32_t)u) << 16; return v.f;
}
__device__ __forceinline__ uint16_t f2bf(float f) {
  union { float f; uint32_t i; } v; v.f = f;
  return (uint16_t)((v.i + 0x7FFFu + ((v.i >> 16) & 1u)) >> 16);
}
__device__ __forceinline__ uint64_t pack4(float a, float b, float c, float d) {
  uint32_t lo = (uint32_t)f2bf(a) | ((uint32_t)f2bf(b) << 16);
  uint32_t hi = (uint32_t)f2bf(c) | ((uint32_t)f2bf(d) << 16);
  return (uint64_t)lo | ((uint64_t)hi << 32);
}
__device__ __forceinline__ float sigm(float x) { return 1.f / (1.f + __expf(-x)); }
__device__ __forceinline__ float tanh_fast(float x) {
  float e = __expf(2.f * x);
  return 1.f - 2.f / (e + 1.f);
}

__device__ __forceinline__ void gll16(const void* g, void* l) {
  __builtin_amdgcn_global_load_lds(
      (const __attribute__((address_space(1))) uint32_t*)g,
      (__attribute__((address_space(3))) uint32_t*)l, 16, 0, 0);
}

// ---------------------------------------------------------------------------
// Persistent LSTM scan. 256 blocks x 256 threads, 1 block/CU.
// Transport: round-5 proven agent-scope (LIC) protocol. sc0/XCD-L2 transport
// was tested rounds 6-9: consistently 2.5x SLOWER (11.8 vs 4.7 us/step),
// insensitive to poll discipline / store scope -> avenue closed.
// Sync (per-wave flags, 2 barriers/step):
//   producer wave: sc1 h-stores -> s_waitcnt vmcnt(0) -> RELAXED agent flag
//     flg[g*64 + win*4 + q] = t+1   (LIC serializes flag-after-data).
//   consumer wave q: polls its 16 producer-wave-q flags (s_sleep(1) backoff)
//     -> workgroup acquire fence (compiler-only) -> sc1 h loads.
// Wave q produces AND consumes batch rows 4q..4q+3 -> wave-local dependency.
// MFMA: wave q = gate q, 2 col-fragments; weights in VGPRs (36 x bf16x8).
// LDS: Ab 16x1152=18432 | gl 4x16x33x4=8448 | bl 512  ~= 27.4 KB
// ---------------------------------------------------------------------------
__global__ __launch_bounds__(256, 1) void lstm_kernel(
    const float* __restrict__ xin, const float* __restrict__ done,
    const float* __restrict__ h0, const float* __restrict__ c0,
    const float* __restrict__ W_ih, const float* __restrict__ W_hh,
    const float* __restrict__ b_ih, const float* __restrict__ b_hh,
    uint16_t* __restrict__ hs, uint32_t* __restrict__ flg,
    float* __restrict__ out)
{
  __shared__ char  Ab[16 * 1152];
  __shared__ float gl[4 * 528];     // [gate][16 rows][33 pad]
  __shared__ float bl[128];         // [gate][32 cols]

  const int wg   = blockIdx.x;
  const int g    = wg >> 4;         // group
  const int win  = wg & 15;         // slot within group -> col block win*32
  const int bg   = g * BW;
  const int tid  = threadIdx.x;
  const int lane = tid & 63;
  const int q    = tid >> 6;        // wave id == gate id

  // one-time: drop stale cache lines from a previous graph replay
  __builtin_amdgcn_fence(__ATOMIC_ACQUIRE, "agent");

  // ---- weights into VGPRs: wave q = gate q, col frags f0=cols 0-15, f1=16-31
  bf16x8 bq0[18], bq1[18];
  {
    const int r0  = q * 512 + win * 32 + (lane & 15);
    const int r1  = r0 + 16;
    const int kg8 = (lane >> 4) * 8;
    #pragma unroll
    for (int ks = 0; ks < 18; ++ks) {
      const float* s0 = (ks < 16)
          ? (W_hh + (size_t)r0 * 512 + ks * 32 + kg8)
          : (W_ih + (size_t)r0 * 64 + (ks - 16) * 32 + kg8);
      const float* s1 = (ks < 16)
          ? (W_hh + (size_t)r1 * 512 + ks * 32 + kg8)
          : (W_ih + (size_t)r1 * 64 + (ks - 16) * 32 + kg8);
      float4 a0 = *(const float4*)s0;
      float4 a1 = *(const float4*)(s0 + 4);
      float4 b0 = *(const float4*)s1;
      float4 b1 = *(const float4*)(s1 + 4);
      bf16x8 va, vb;
      va[0] = (short)f2bf(a0.x); va[1] = (short)f2bf(a0.y);
      va[2] = (short)f2bf(a0.z); va[3] = (short)f2bf(a0.w);
      va[4] = (short)f2bf(a1.x); va[5] = (short)f2bf(a1.y);
      va[6] = (short)f2bf(a1.z); va[7] = (short)f2bf(a1.w);
      vb[0] = (short)f2bf(b0.x); vb[1] = (short)f2bf(b0.y);
      vb[2] = (short)f2bf(b0.z); vb[3] = (short)f2bf(b0.w);
      vb[4] = (short)f2bf(b1.x); vb[5] = (short)f2bf(b1.y);
      vb[6] = (short)f2bf(b1.z); vb[7] = (short)f2bf(b1.w);
      bq0[ks] = va; bq1[ks] = vb;
    }
  }
  if (tid < 128) {
    int gq = tid >> 5, c = tid & 31;
    int grow = gq * 512 + win * 32 + c;
    bl[tid] = b_ih[grow] + b_hh[grow];
  }

  const int b_loc = tid >> 4;        // 0..15 (batch row within group)
  const int n0    = (tid & 15) * 2;  // col pair within WG's 32 cols
  float creg0 = c0[(size_t)(bg + b_loc) * HID + win * 32 + n0];
  float creg1 = c0[(size_t)(bg + b_loc) * HID + win * 32 + n0 + 1];

  const int sr  = tid >> 4;          // x staging row (0..15)
  const int sc4 = (tid & 15) * 4;    // x col base (4 floats/thread)
  const int rw  = q * 4;             // wave's 4 h rows (produce AND consume)

  __syncthreads();

  for (int t = 0; t < T_STEPS; ++t) {
    // ---- hoisted loads (overlap the poll): x_t, done values ----
    const float* xp = xin + ((size_t)t * BSZ + bg + sr) * OBSD + sc4;
    float4 xa = *(const float4*)xp;
    float dvs[4];
    #pragma unroll
    for (int r8 = 0; r8 < 4; ++r8)
      dvs[r8] = done[(size_t)t * BSZ + bg + rw + r8];
    float dv_b = done[(size_t)t * BSZ + bg + b_loc];

    // stage x_t into Ab (all MFMA(t-1) finished before gl-barrier -> no race)
    *(uint64_t*)(Ab + ((sr * 1152 + 1024 + sc4 * 2) ^ ((sr & 7) << 4))) =
        pack4(xa.x, xa.y, xa.z, xa.w);

    // ---- wave q waits for its 16 producer-wave-q flags (step t-1) ----
    if (t > 0) {
      for (;;) {
        uint32_t f = (lane < WPG)
            ? __hip_atomic_load(flg + g * 64 + lane * 4 + q,
                                __ATOMIC_RELAXED, __HIP_MEMORY_SCOPE_AGENT)
            : 0xFFFFFFFFu;
        if (__all((int)(f >= (uint32_t)t))) break;
        __builtin_amdgcn_s_sleep(1);
      }
      __builtin_amdgcn_fence(__ATOMIC_ACQUIRE, "workgroup");
    }

    // ---- stage h_{t-1} rows rw..rw+3 (coalesced 512B per instruction) ----
    if (t == 0) {
      #pragma unroll
      for (int r8 = 0; r8 < 4; ++r8) {
        int r = rw + r8;
        uint64_t v0 = 0, v1 = 0;
        if (dvs[r8] <= 0.5f) {
          const float* hp = h0 + (size_t)(bg + r) * HID;
          float4 ha = *(const float4*)(hp + lane * 4);
          float4 hb = *(const float4*)(hp + 256 + lane * 4);
          v0 = pack4(ha.x, ha.y, ha.z, ha.w);
          v1 = pack4(hb.x, hb.y, hb.z, hb.w);
        }
        *(uint64_t*)(Ab + ((r * 1152 + lane * 8) ^ ((r & 7) << 4))) = v0;
        *(uint64_t*)(Ab + ((r * 1152 + 512 + lane * 8) ^ ((r & 7) << 4))) = v1;
      }
    } else {
      #pragma unroll
      for (int r8 = 0; r8 < 4; ++r8) {
        int r = rw + r8;
        const uint64_t* hrow =
            (const uint64_t*)hs + ((size_t)(t - 1) * BSZ + bg + r) * 128;
        uint64_t v0 = __hip_atomic_load(hrow + lane, __ATOMIC_RELAXED, __HIP_MEMORY_SCOPE_AGENT);
        uint64_t v1 = __hip_atomic_load(hrow + 64 + lane, __ATOMIC_RELAXED, __HIP_MEMORY_SCOPE_AGENT);
        if (dvs[r8] > 0.5f) { v0 = 0; v1 = 0; }
        *(uint64_t*)(Ab + ((r * 1152 + lane * 8) ^ ((r & 7) << 4))) = v0;
        *(uint64_t*)(Ab + ((r * 1152 + 512 + lane * 8) ^ ((r & 7) << 4))) = v1;
      }
    }
    __syncthreads();   // barrier 1: all 16 rows staged

    // ---- MFMA: wave q -> gate q, [16 rows x 32 cols], K=576 ----
    f32x4 ac0 = {0.f, 0.f, 0.f, 0.f};
    f32x4 ac1 = {0.f, 0.f, 0.f, 0.f};
    {
      const int ar = lane & 15;
      const int kg = lane >> 4;
      #pragma unroll
      for (int ks = 0; ks < 18; ++ks) {
        int kb = (ks * 32 + kg * 8) * 2;
        bf16x8 a = *(const bf16x8*)(Ab + ((ar * 1152 + kb) ^ ((ar & 7) << 4)));
        ac0 = __builtin_amdgcn_mfma_f32_16x16x32_bf16(a, bq0[ks], ac0, 0, 0, 0);
        ac1 = __builtin_amdgcn_mfma_f32_16x16x32_bf16(a, bq1[ks], ac1, 0, 0, 0);
      }
    }
    // ---- gates -> LDS exchange (rows padded to 33 words) ----
    {
      int c  = lane & 15;
      int rb = (lane >> 4) * 4;
      #pragma unroll
      for (int r = 0; r < 4; ++r) {
        gl[q * 528 + (rb + r) * 33 + c]      = ac0[r];
        gl[q * 528 + (rb + r) * 33 + 16 + c] = ac1[r];
      }
    }
    __syncthreads();   // barrier 2: all 4 gates exchanged

    // ---- cell update (c lives in registers across all 512 steps) ----
    {
      float m = dv_b > 0.5f ? 0.f : 1.f;
      float h0v, h1v;
      {
        float I = gl[b_loc * 33 + n0]          + bl[n0];
        float F = gl[528 + b_loc * 33 + n0]    + bl[32 + n0];
        float G = gl[1056 + b_loc * 33 + n0]   + bl[64 + n0];
        float O = gl[1584 + b_loc * 33 + n0]   + bl[96 + n0];
        float cc = creg0 * m;
        cc = sigm(F) * cc + sigm(I) * tanh_fast(G);
        creg0 = cc;
        h0v = sigm(O) * tanh_fast(cc);
      }
      {
        int n1 = n0 + 1;
        float I = gl[b_loc * 33 + n1]          + bl[n1];
        float F = gl[528 + b_loc * 33 + n1]    + bl[32 + n1];
        float G = gl[1056 + b_loc * 33 + n1]   + bl[64 + n1];
        float O = gl[1584 + b_loc * 33 + n1]   + bl[96 + n1];
        float cc = creg1 * m;
        cc = sigm(F) * cc + sigm(I) * tanh_fast(G);
        creg1 = cc;
        h1v = sigm(O) * tanh_fast(cc);
      }
      uint32_t pk = (uint32_t)f2bf(h0v) | ((uint32_t)f2bf(h1v) << 16);
      uint32_t* hp = (uint32_t*)(hs + ((size_t)t * BSZ + bg + b_loc) * HID + win * 32 + n0);
      __hip_atomic_store(hp, pk, __ATOMIC_RELAXED, __HIP_MEMORY_SCOPE_AGENT);
      if (t == T_STEPS - 1) {
        size_t ob = (size_t)(bg + b_loc) * HID + win * 32 + n0;
        out[NROWS + ob]         = h0v;
        out[NROWS + ob + 1]     = h1v;
        out[2 * NROWS + ob]     = creg0;
        out[2 * NROWS + ob + 1] = creg1;
      }
    }
    // per-wave flag: own h stores drained at the LIC -> publish immediately
    asm volatile("s_waitcnt vmcnt(0)" ::: "memory");
    if ((tid & 63) == 0)
      __hip_atomic_store(flg + g * 64 + win * 4 + q, (uint32_t)(t + 1),
                         __ATOMIC_RELAXED, __HIP_MEMORY_SCOPE_AGENT);
  }
}

// ---------------------------------------------------------------------------
// Per-row LayerNorm stats from bf16 hidden: rstd[m], murs[m] = mu*rstd.
// ---------------------------------------------------------------------------
__global__ void ln_stats_kernel(const uint16_t* __restrict__ hsrc,
                                float* __restrict__ rstd_a, float* __restrict__ murs_a)
{
  const int lane = threadIdx.x & 63;
  const size_t row = (size_t)blockIdx.x * 4 + (threadIdx.x >> 6);
  bf16x8 v = *(const bf16x8*)(hsrc + row * 512 + lane * 8);
  float s = 0.f, s2 = 0.f;
  #pragma unroll
  for (int j = 0; j < 8; ++j) { float f = bf2f((uint16_t)v[j]); s += f; s2 += f * f; }
  #pragma unroll
  for (int o = 1; o < 64; o <<= 1) { s += __shfl_xor(s, o); s2 += __shfl_xor(s2, o); }
  if (lane == 0) {
    float mu  = s * (1.f / 512.f);
    float var = s2 * (1.f / 512.f) - mu * mu;
    float rs  = rsqrtf(var + 1e-5f);
    rstd_a[row] = rs;
    murs_a[row] = mu * rs;
  }
}

// ---------------------------------------------------------------------------
// u[n] = sum_k ln_b[k]*W1[n,k] + b1[n] ;  v[n] = sum_k ln_g[k]*W1[n,k]
// ---------------------------------------------------------------------------
__global__ void uv_kernel(const float* __restrict__ W1, const float* __restrict__ ln_g,
                          const float* __restrict__ ln_b, const float* __restrict__ b1,
                          float* __restrict__ u, float* __restrict__ v)
{
  const int lane = threadIdx.x & 63;
  const int row  = blockIdx.x * 4 + (threadIdx.x >> 6);
  const float* wp = W1 + (size_t)row * 512 + lane * 8;
  float4 w0 = *(const float4*)wp;
  float4 w1 = *(const float4*)(wp + 4);
  float4 g0 = *(const float4*)(ln_g + lane * 8);
  float4 g1 = *(const float4*)(ln_g + lane * 8 + 4);
  float4 b0 = *(const float4*)(ln_b + lane * 8);
  float4 b1v = *(const float4*)(ln_b + lane * 8 + 4);
  float su = b0.x * w0.x + b0.y * w0.y + b0.z * w0.z + b0.w * w0.w
           + b1v.x * w1.x + b1v.y * w1.y + b1v.z * w1.z + b1v.w * w1.w;
  float sv = g0.x * w0.x + g0.y * w0.y + g0.z * w0.z + g0.w * w0.w
           + g1.x * w1.x + g1.y * w1.y + g1.z * w1.z + g1.w * w1.w;
  #pragma unroll
  for (int o = 1; o < 64; o <<= 1) { su += __shfl_xor(su, o); sv += __shfl_xor(sv, o); }
  if (lane == 0) { u[row] = su + b1[row]; v[row] = sv; }
}

// ---------------------------------------------------------------------------
// Fused GEMM: C = tanh(epilogue(A[64 rows, K=512] @ W[,512]^T))
// MODE 0: LN-affine epilogue  tanh(rstd_m*G - murs_m*v_n + u_n)   (u has +b1)
// MODE 1: bias epilogue       tanh(G + bias_n)
// ---------------------------------------------------------------------------
template<int MODE>
__global__ __launch_bounds__(256, 2) void gemm_fused(
    const uint16_t* __restrict__ Abase, const uint16_t* __restrict__ W,
    uint16_t* __restrict__ C, int ntiles,
    const float* __restrict__ rstd_a, const float* __restrict__ murs_a,
    const float* __restrict__ uvec, const float* __restrict__ vvec,
    const float* __restrict__ bias)
{
  __shared__ uint16_t At[64 * 512];   // 65536 B
  const int tid  = threadIdx.x;
  const int lane = tid & 63;
  const int wv   = tid >> 6;
  const size_t mbase = (size_t)blockIdx.x * 64;

  for (int r8 = 0; r8 < 16; ++r8) {
    int row = wv * 16 + r8;
    int sb  = (lane * 16) ^ ((row & 7) << 4);
    gll16(Abase + (mbase + row) * 512 + sb / 2, At + row * 512);
  }
  __syncthreads();

  const int fr = lane & 15, kg = lane >> 4;
  const int mloc = (wv & 1) * 32;
  const int nhalf = (wv >> 1) * 64;

  for (int nt = 0; nt < ntiles; ++nt) {
    const int nbase = nt * 128 + nhalf;
    f32x4 vz = {0.f, 0.f, 0.f, 0.f};
    f32x4 acc[4][2];
    #pragma unroll
    for (int i = 0; i < 4; ++i) { acc[i][0] = vz; acc[i][1] = vz; }

    #pragma unroll 4
    for (int kb = 0; kb < 16; ++kb) {
      const int ke = kb * 32 + kg * 8;
      bf16x8 wf[4];
      #pragma unroll
      for (int i = 0; i < 4; ++i)
        wf[i] = *(const bf16x8*)(W + (size_t)(nbase + i * 16 + fr) * 512 + ke);
      bf16x8 af[2];
      #pragma unroll
      for (int j = 0; j < 2; ++j) {
        int mr = mloc + j * 16 + fr;
        af[j] = *(const bf16x8*)((const char*)At + ((mr * 1024 + ke * 2) ^ ((mr & 7) << 4)));
      }
      #pragma unroll
      for (int i = 0; i < 4; ++i)
        #pragma unroll
        for (int j = 0; j < 2; ++j)
          acc[i][j] = __builtin_amdgcn_mfma_f32_16x16x32_bf16(wf[i], af[j], acc[i][j], 0, 0, 0);
    }

    #pragma unroll
    for (int j = 0; j < 2; ++j) {
      size_t m = mbase + mloc + j * 16 + fr;
      float rs = 0.f, mrs = 0.f;
      if constexpr (MODE == 0) { rs = rstd_a[m]; mrs = murs_a[m]; }
      #pragma unroll
      for (int i = 0; i < 4; ++i) {
        int n = nbase + i * 16 + kg * 4;
        float o0, o1, o2, o3;
        if constexpr (MODE == 0) {
          float4 uu = *(const float4*)(uvec + n);
          float4 vv = *(const float4*)(vvec + n);
          o0 = tanh_fast(rs * acc[i][j][0] - mrs * vv.x + uu.x);
          o1 = tanh_fast(rs * acc[i][j][1] - mrs * vv.y + uu.y);
          o2 = tanh_fast(rs * acc[i][j][2] - mrs * vv.z + uu.z);
          o3 = tanh_fast(rs * acc[i][j][3] - mrs * vv.w + uu.w);
        } else {
          float4 bb = *(const float4*)(bias + n);
          o0 = tanh_fast(acc[i][j][0] + bb.x);
          o1 = tanh_fast(acc[i][j][1] + bb.y);
          o2 = tanh_fast(acc[i][j][2] + bb.z);
          o3 = tanh_fast(acc[i][j][3] + bb.w);
        }
        uint32_t lo = (uint32_t)f2bf(o0) | ((uint32_t)f2bf(o1) << 16);
        uint32_t hi = (uint32_t)f2bf(o2) | ((uint32_t)f2bf(o3) << 16);
        *(uint64_t*)(C + m * 512 + n) = (uint64_t)lo | ((uint64_t)hi << 32);
      }
    }
    __syncthreads();
  }
}

// ---------------------------------------------------------------------------
// value[m] = a2[m,:256] . Wv + bv   (a2 at stride 512; one wave per row)
// ---------------------------------------------------------------------------
__global__ void gemv_kernel(const uint16_t* __restrict__ a2, const float* __restrict__ Wv,
                            const float* __restrict__ bv, float* __restrict__ outv)
{
  const int lane = threadIdx.x & 63;
  const size_t row = (size_t)blockIdx.x * 4 + (threadIdx.x >> 6);
  const uint16_t* p = a2 + row * 512 + lane * 4;
  uint64_t v = *(const uint64_t*)p;
  float4 w = *(const float4*)(Wv + lane * 4);
  float d = bf2f((uint16_t)(v & 0xFFFF)) * w.x
          + bf2f((uint16_t)((v >> 16) & 0xFFFF)) * w.y
          + bf2f((uint16_t)((v >> 32) & 0xFFFF)) * w.z
          + bf2f((uint16_t)((v >> 48) & 0xFFFF)) * w.w;
  #pragma unroll
  for (int o = 1; o < 64; o <<= 1) d += __shfl_xor(d, o);
  if (lane == 0) outv[row] = d + bv[0];
}

// ---------------------------------------------------------------------------
// W1 (fold ln_g into columns) then W2, fp32 -> bf16 contiguous.
// ---------------------------------------------------------------------------
__global__ void wconv_kernel(const float* __restrict__ W1, const float* __restrict__ W2,
                             const float* __restrict__ ln_g, uint16_t* __restrict__ dst)
{
  int idx = blockIdx.x * 256 + threadIdx.x;
  int i4 = idx * 4;
  float4 v;
  if (i4 < 262144) {
    v = *(const float4*)(W1 + i4);
    int c = i4 & 511;
    float4 gv = *(const float4*)(ln_g + c);
    v.x *= gv.x; v.y *= gv.y; v.z *= gv.z; v.w *= gv.w;
  } else {
    v = *(const float4*)(W2 + (i4 - 262144));
  }
  uint32_t lo = (uint32_t)f2bf(v.x) | ((uint32_t)f2bf(v.y) << 16);
  uint32_t hi = (uint32_t)f2bf(v.z) | ((uint32_t)f2bf(v.w) << 16);
  *(uint64_t*)(dst + i4) = (uint64_t)lo | ((uint64_t)hi << 32);
}

extern "C" void kernel_launch(void* const* d_in, const int* in_sizes, int n_in,
                              void* d_out, int out_size, void* d_ws, size_t ws_size,
                              hipStream_t stream)
{
  (void)in_sizes; (void)n_in;
  const float* x    = (const float*)d_in[0];
  const float* done = (const float*)d_in[1];
  const float* h0   = (const float*)d_in[2];
  const float* c0   = (const float*)d_in[3];
  const float* W_ih = (const float*)d_in[4];
  const float* W_hh = (const float*)d_in[5];
  const float* b_ih = (const float*)d_in[6];
  const float* b_hh = (const float*)d_in[7];
  const float* ln_g = (const float*)d_in[8];
  const float* ln_b = (const float*)d_in[9];
  const float* W1   = (const float*)d_in[10];
  const float* b1   = (const float*)d_in[11];
  const float* W2   = (const float*)d_in[12];
  const float* b2   = (const float*)d_in[13];
  const float* Wv   = (const float*)d_in[14];
  const float* bv   = (const float*)d_in[15];
  float* out = (float*)d_out;
  char* ws = (char*)d_ws;

  // ws layout (bytes):
  //   0        flg      4096     (16 groups x 64 per-wave flags, 256B/group)
  //   16384    wbf      786432   (bf16 W1g | W2)
  //   802816   u,v      4096     (512 f32 each)
  //   806912   rstd     524288
  //   1331200  murs     524288
  //   2097152  hs       134217728  (bf16 [T*B,512]; later a1 in-place, a2 cols 0..255)
  constexpr size_t NEED = 2097152ULL + 134217728ULL;
  if (ws_size < NEED) {
    hipMemsetAsync(d_out, 0, (size_t)out_size * 4, stream);
    return;
  }
  uint32_t* flg  = (uint32_t*)ws;
  uint16_t* wbf  = (uint16_t*)(ws + 16384);
  float*    uv_u = (float*)(ws + 802816);
  float*    uv_v = (float*)(ws + 802816 + 2048);
  float*    rstd = (float*)(ws + 806912);
  float*    murs = (float*)(ws + 1331200);
  uint16_t* hsb  = (uint16_t*)(ws + 2097152);

  hipMemsetAsync(ws, 0, 16384, stream);
  hipLaunchKernelGGL(wconv_kernel, dim3(384), dim3(256), 0, stream, W1, W2, ln_g, wbf);
  hipLaunchKernelGGL(uv_kernel, dim3(128), dim3(256), 0, stream, W1, ln_g, ln_b, b1, uv_u, uv_v);
  hipLaunchKernelGGL(lstm_kernel, dim3(256), dim3(256), 0, stream,
                     x, done, h0, c0, W_ih, W_hh, b_ih, b_hh, hsb, flg, out);
  hipLaunchKernelGGL(ln_stats_kernel, dim3(32768), dim3(256), 0, stream, hsb, rstd, murs);
  // GEMM1: a1 = tanh(LN(h) @ W1^T + b1), in-place over hs
  hipLaunchKernelGGL((gemm_fused<0>), dim3(2048), dim3(256), 0, stream,
                     hsb, wbf, hsb, 4, rstd, murs, uv_u, uv_v, (const float*)nullptr);
  // GEMM2: a2 = tanh(a1 @ W2^T + b2), in-place over hs cols [0,256)
  hipLaunchKernelGGL((gemm_fused<1>), dim3(2048), dim3(256), 0, stream,
                     hsb, wbf + 262144, hsb, 2,
                     (const float*)nullptr, (const float*)nullptr,
                     (const float*)nullptr, (const float*)nullptr, b2);
  hipLaunchKernelGGL(gemv_kernel, dim3(32768), dim3(256), 0, stream, hsb, Wv, bv, out);
}